// Round 6
// baseline (697.223 us; speedup 1.0000x reference)
//
#include <hip/hip_runtime.h>

// GRU scan: B=2048, T=2048, D=3, H=32. out[b,t] = h_new[b,t][0].
// Round-8 resubmit (R5 bench was an infra failure: container died twice;
// kernel never ran). R7 structure + x off the critical chain.
// R7 post-mortem: wall/step = max(chain C, W x issue I); R7 was chain-bound
// at C~750cy, and ~250cy of that was per-step GLOBAL x loads (inp streams
// from HBM; vmcnt(0) before the input projections exposes the miss).
// This round restores the R5-proven x pipeline under the R7 layout:
//  - x chunk (32 steps x 3 floats per seq) global->reg prefetched one chunk
//    ahead; reg->LDS staged at chunk top; per-step x = 3 broadcast
//    ds_read_b32 that queue AHEAD of the h write->read in the same-wave
//    in-order DS pipe -> x latency never touches the chain.
//  - aR/aZ folded into dot-accumulator inits (-2 chain adds).
//  - everything else unchanged from R7 (2 seqs/wave, full-unit ownership,
//    96 FMA/step, waitless same-wave DS ordering, 1 wave/SIMD).

#define GRU_B 2048
#define GRU_T 2048
#define GRU_D 3
#define GRU_H 32
#define CHUNK 32  // timesteps per x-staging chunk (96 floats per seq)

__device__ __forceinline__ float fast_sigmoid(float x) {
    float e = __expf(-x);                    // v_mul(log2e)+v_exp
    return __builtin_amdgcn_rcpf(1.0f + e);  // e=inf -> 0 (correct limit)
}
__device__ __forceinline__ float fast_tanh(float x) {
    float e = __expf(2.0f * x);              // overflow -> inf -> tanh=1
    return 1.0f - 2.0f * __builtin_amdgcn_rcpf(e + 1.0f);
}

__global__ __launch_bounds__(64, 1) void gru_scan_kernel(
    const float* __restrict__ inp,     // [B, T, D]
    const float* __restrict__ w_ih,    // [3H, D]
    const float* __restrict__ w_hh,    // [3H, H]
    const float* __restrict__ bias,    // [3H]
    const float* __restrict__ bias_n,  // [H]
    float* __restrict__ out)           // [B, T]
{
    // h: seq-A at floats [0..31], seq-B at [48..79] (16-bank offset keeps
    // the two broadcast groups of every b128 quad on disjoint banks; the
    // h-write is exactly 2 lanes/bank = free).
    __shared__ __align__(16) float h2[80];
    // x: seq-A chunk at [0..95], seq-B at [96..191] (2-addr/bank = free).
    __shared__ __align__(16) float x_lds[2 * CHUNK * GRU_D];

    const int lane = threadIdx.x;   // 0..63
    const int p    = lane & 31;     // owned hidden unit
    const int hf   = lane >> 5;     // 0: seq 2b, 1: seq 2b+1
    const size_t seq = 2 * (size_t)blockIdx.x + hf;

    // ---- weights for unit p: rows p (r), 32+p (z), 64+p (n) ----
    float wr[32], wz[32], wn[32];
    {
        const float4* pr = (const float4*)(w_hh + (size_t)p * GRU_H);
        const float4* pz = (const float4*)(w_hh + (size_t)(GRU_H + p) * GRU_H);
        const float4* pn = (const float4*)(w_hh + (size_t)(2 * GRU_H + p) * GRU_H);
#pragma unroll
        for (int q = 0; q < 8; ++q) {
            float4 R = pr[q], Z = pz[q], N = pn[q];
            wr[4*q+0]=R.x; wr[4*q+1]=R.y; wr[4*q+2]=R.z; wr[4*q+3]=R.w;
            wz[4*q+0]=Z.x; wz[4*q+1]=Z.y; wz[4*q+2]=Z.z; wz[4*q+3]=Z.w;
            wn[4*q+0]=N.x; wn[4*q+1]=N.y; wn[4*q+2]=N.z; wn[4*q+3]=N.w;
        }
    }
    float wir[GRU_D], wiz[GRU_D], win[GRU_D];
#pragma unroll
    for (int d = 0; d < GRU_D; ++d) {
        wir[d] = w_ih[(size_t)p * GRU_D + d];
        wiz[d] = w_ih[(size_t)(GRU_H + p) * GRU_D + d];
        win[d] = w_ih[(size_t)(2 * GRU_H + p) * GRU_D + d];
    }
    const float bR = bias[p];
    const float bZ = bias[GRU_H + p];
    const float bN = bias[2 * GRU_H + p] + bias_n[p];

    const float* xp = inp + seq * (size_t)(GRU_T * GRU_D);
    float*       ob = out + seq * (size_t)GRU_T;

    const int hbase = 48 * hf;
    float* hw = h2 + hbase + p;                      // my h slot
    const float4* hv = (const float4*)(h2 + hbase);  // my seq's h vector

    // x staging pointers: 32 lanes per half cover 96 floats in 3 strides.
    float* xw = x_lds + 96 * hf + p;                 // write slot base
    const float* xr = x_lds + 96 * hf;               // per-step read base

    float h = 0.0f;
    *hw = 0.0f;  // zero init; same-wave DS order covers the first gather

    // prefetch chunk 0 into regs (coalesced 128B per half per load)
    float xa = xp[p];
    float xb2 = xp[32 + p];
    float xc2 = xp[64 + p];

    for (int c = 0; c < GRU_T / CHUNK; ++c) {
        // ---- stage current chunk (regs -> LDS), prefetch next chunk ----
        xw[0]  = xa;
        xw[32] = xb2;
        xw[64] = xc2;
        if (c + 1 < GRU_T / CHUNK) {
            const size_t nb = (size_t)(c + 1) * (CHUNK * GRU_D);
            xa  = xp[nb + p];
            xb2 = xp[nb + 32 + p];
            xc2 = xp[nb + 64 + p];
        }
        // staging writes precede this chunk's x reads in the same-wave
        // in-order DS queue: no explicit wait needed.

        float outreg = 0.0f;
#pragma unroll 8
        for (int s = 0; s < CHUNK; ++s) {
            // x broadcast: 3 ds_read_b32 (uniform per half) — these queue
            // BEFORE the h write/reads, so their data arrives first.
            const float x0 = xr[3 * s + 0];
            const float x1 = xr[3 * s + 1];
            const float x2 = xr[3 * s + 2];

            // h all-gather: 8 x ds_read_b128, broadcast per half,
            // disjoint banks between halves.
            float4 hk[8];
#pragma unroll
            for (int q = 0; q < 8; ++q) hk[q] = hv[q];

            // input projections (x-only; off the h chain)
            const float aR = fmaf(wir[2], x2, fmaf(wir[1], x1, fmaf(wir[0], x0, bR)));
            const float aZ = fmaf(wiz[2], x2, fmaf(wiz[1], x1, fmaf(wiz[0], x0, bZ)));
            const float aN = fmaf(win[2], x2, fmaf(win[1], x1, fmaf(win[0], x0, bN)));

            // 96 FMAs: full K=32 dot for r, z, n rows (2 accs each);
            // aR/aZ folded into the accumulator inits.
            float r0=aR, r1=0.f, z0=aZ, z1=0.f, n0=0.f, n1=0.f;
#pragma unroll
            for (int q = 0; q < 8; ++q) {
                const float4 v = hk[q];
                r0 = fmaf(wr[4*q+0], v.x, r0); r1 = fmaf(wr[4*q+1], v.y, r1);
                r0 = fmaf(wr[4*q+2], v.z, r0); r1 = fmaf(wr[4*q+3], v.w, r1);
                z0 = fmaf(wz[4*q+0], v.x, z0); z1 = fmaf(wz[4*q+1], v.y, z1);
                z0 = fmaf(wz[4*q+2], v.z, z0); z1 = fmaf(wz[4*q+3], v.w, z1);
                n0 = fmaf(wn[4*q+0], v.x, n0); n1 = fmaf(wn[4*q+1], v.y, n1);
                n0 = fmaf(wn[4*q+2], v.z, n0); n1 = fmaf(wn[4*q+3], v.w, n1);
            }
            const float rg = fast_sigmoid(r0 + r1);
            const float zg = fast_sigmoid(z0 + z1);
            const float ng = fast_tanh(fmaf(rg, n0 + n1, aN));
            const float hnew = fmaf(zg, h - ng, ng);   // (1-z)*n + z*h

            // hk[0].x = h[0] BEFORE this step = output of step s-1 (own seq)
            if (p == s - 1) outreg = hk[0].x;

            h = hnew;
            *hw = h;  // next gather is ordered behind this write (same wave)
        }
        // output of step 31: h[0] after last step (DS-ordered read)
        {
            const float h0 = h2[hbase];
            if (p == CHUNK - 1) outreg = h0;
        }
        ob[c * CHUNK + p] = outreg;  // 2 x 128B coalesced stores (per half)
    }
}

extern "C" void kernel_launch(void* const* d_in, const int* in_sizes, int n_in,
                              void* d_out, int out_size, void* d_ws, size_t ws_size,
                              hipStream_t stream) {
    const float* inp    = (const float*)d_in[0];
    const float* w_ih   = (const float*)d_in[1];
    const float* w_hh   = (const float*)d_in[2];
    const float* bias   = (const float*)d_in[3];
    const float* bias_n = (const float*)d_in[4];
    float* out = (float*)d_out;

    dim3 grid(GRU_B / 2);
    dim3 block(64);
    gru_scan_kernel<<<grid, block, 0, stream>>>(inp, w_ih, w_hh, bias, bias_n, out);
}

// Round 7
// 612.789 us; speedup vs baseline: 1.1378x; 1.1378x over previous
//
#include <hip/hip_runtime.h>

// GRU scan: B=2048, T=2048, D=3, H=32. out[b,t] = h_new[b,t][0].
// Round-9: all-register h exchange. R5/R7/R8 converge to 750-830 cy/step
// with ~500-600 cy being the LDS h write->read round-trip + waits — the
// invariant bottleneck. This round removes LDS from the recurrence:
//  - lane layout: 16-lane rows; rows {0,2}=seq A, rows {1,3}=seq B
//    (seq = bit4). unit p = (lane&15) + 16*(lane>>5).
//  - own 16-unit block all-gather: 15 v_mov_dpp row_ror:j (VALU);
//  - other block: permlane32_swap per rotation reg (lane^32 keeps bit4 ->
//    same seq, other block). Both probed at runtime (ballot-verified);
//    any mismatch -> R8-style LDS fallback loop.
//  - weights pre-permuted at init to match rotation order (dir-aware).
//  - DS traffic/step: 3 broadcast x reads + 1 capture write (off-chain);
//    out staged in out_stage[2][32], stored coalesced at chunk end.
//  - 1024 blocks x 1 wave, __launch_bounds__(64,1).

#define GRU_B 2048
#define GRU_T 2048
#define GRU_D 3
#define GRU_H 32
#define CHUNK 32

typedef unsigned int uint2v __attribute__((ext_vector_type(2)));

__device__ __forceinline__ float fast_sigmoid(float x) {
    float e = __expf(-x);                    // v_mul(log2e)+v_exp
    return __builtin_amdgcn_rcpf(1.0f + e);  // e=inf -> 0 (correct limit)
}
__device__ __forceinline__ float fast_tanh(float x) {
    float e = __expf(2.0f * x);              // overflow -> inf -> tanh=1
    return 1.0f - 2.0f * __builtin_amdgcn_rcpf(e + 1.0f);
}

// DPP row_ror:N = 0x120+N; all rows/banks, no bound ctrl.
#define DPPF(v, CTRL) __int_as_float(__builtin_amdgcn_update_dpp( \
    0, __float_as_int(v), (CTRL), 0xF, 0xF, false))

template<bool SEL>
__device__ __forceinline__ float swap32(float v) {
    uint2v r = __builtin_amdgcn_permlane32_swap(
        __float_as_uint(v), __float_as_uint(v), false, false);
    return __uint_as_float(SEL ? r.x : r.y);
}

// ---------------- fast path: register h, DPP + permlane32 ----------------
template<bool SEL>
__device__ void gru_fast(
    const float* __restrict__ xp, float* __restrict__ ob,
    const float* __restrict__ w_ih, const float* __restrict__ w_hh,
    const float* __restrict__ bias, const float* __restrict__ bias_n,
    float* __restrict__ x_lds, float* __restrict__ out_stage,
    int lane, int hf, int p, int dir)
{
    const int li = lane & 15;          // index within 16-row
    const int bb = 16 * (lane >> 5);   // own unit-block base (0 or 16)

    // weights permuted to rotation order: FMA j pairs rotation j.
    float wrO[16], wrX[16], wzO[16], wzX[16], wnO[16], wnX[16];
#pragma unroll
    for (int j = 0; j < 16; ++j) {
        const int kk = (li + dir * j + 16) & 15;
        const int kown = bb + kk;
        const int koth = (bb ^ 16) + kk;
        wrO[j] = w_hh[(size_t)p * GRU_H + kown];
        wrX[j] = w_hh[(size_t)p * GRU_H + koth];
        wzO[j] = w_hh[(size_t)(GRU_H + p) * GRU_H + kown];
        wzX[j] = w_hh[(size_t)(GRU_H + p) * GRU_H + koth];
        wnO[j] = w_hh[(size_t)(2 * GRU_H + p) * GRU_H + kown];
        wnX[j] = w_hh[(size_t)(2 * GRU_H + p) * GRU_H + koth];
    }
    float wir[GRU_D], wiz[GRU_D], win[GRU_D];
#pragma unroll
    for (int d = 0; d < GRU_D; ++d) {
        wir[d] = w_ih[(size_t)p * GRU_D + d];
        wiz[d] = w_ih[(size_t)(GRU_H + p) * GRU_D + d];
        win[d] = w_ih[(size_t)(2 * GRU_H + p) * GRU_D + d];
    }
    const float bR = bias[p];
    const float bZ = bias[GRU_H + p];
    const float bN = bias[2 * GRU_H + p] + bias_n[p];

    float* xw = x_lds + 96 * hf;
    const float* xr = x_lds + 96 * hf;
    float* osw = out_stage + 32 * hf;
    const bool cap = (lane & 47) == 0;  // lanes 0,16 = unit 0 of each seq

    float h = 0.0f;
    // prefetch chunk 0 (each 16-lane run = 64B contiguous per seq)
    float xa = xp[p], xb = xp[32 + p], xc = xp[64 + p];

    for (int c = 0; c < GRU_T / CHUNK; ++c) {
        xw[p] = xa; xw[32 + p] = xb; xw[64 + p] = xc;
        if (c + 1 < GRU_T / CHUNK) {
            const size_t nb = (size_t)(c + 1) * (CHUNK * GRU_D);
            xa = xp[nb + p]; xb = xp[nb + 32 + p]; xc = xp[nb + 64 + p];
        }
#pragma unroll 8
        for (int s = 0; s < CHUNK; ++s) {
            const float x0 = xr[3 * s + 0];
            const float x1 = xr[3 * s + 1];
            const float x2 = xr[3 * s + 2];

            // own-block all-gather: 15 DPP rotations (VALU pipe)
            float hr_[16];
            hr_[0] = h;
            hr_[1]  = DPPF(h, 0x121); hr_[2]  = DPPF(h, 0x122);
            hr_[3]  = DPPF(h, 0x123); hr_[4]  = DPPF(h, 0x124);
            hr_[5]  = DPPF(h, 0x125); hr_[6]  = DPPF(h, 0x126);
            hr_[7]  = DPPF(h, 0x127); hr_[8]  = DPPF(h, 0x128);
            hr_[9]  = DPPF(h, 0x129); hr_[10] = DPPF(h, 0x12A);
            hr_[11] = DPPF(h, 0x12B); hr_[12] = DPPF(h, 0x12C);
            hr_[13] = DPPF(h, 0x12D); hr_[14] = DPPF(h, 0x12E);
            hr_[15] = DPPF(h, 0x12F);
            // other block: lane^32 (same seq, other 16 units)
            float ho_[16];
#pragma unroll
            for (int j = 0; j < 16; ++j) ho_[j] = swap32<SEL>(hr_[j]);

            const float aR = fmaf(wir[2], x2, fmaf(wir[1], x1, fmaf(wir[0], x0, bR)));
            const float aZ = fmaf(wiz[2], x2, fmaf(wiz[1], x1, fmaf(wiz[0], x0, bZ)));
            const float aN = fmaf(win[2], x2, fmaf(win[1], x1, fmaf(win[0], x0, bN)));

            float r0 = aR, r1 = 0.f, z0 = aZ, z1 = 0.f, n0 = 0.f, n1 = 0.f;
#pragma unroll
            for (int j = 0; j < 16; ++j) {
                r0 = fmaf(wrO[j], hr_[j], r0);
                r1 = fmaf(wrX[j], ho_[j], r1);
                z0 = fmaf(wzO[j], hr_[j], z0);
                z1 = fmaf(wzX[j], ho_[j], z1);
                n0 = fmaf(wnO[j], hr_[j], n0);
                n1 = fmaf(wnX[j], ho_[j], n1);
            }
            const float rg = fast_sigmoid(r0 + r1);
            const float zg = fast_sigmoid(z0 + z1);
            const float ng = fast_tanh(fmaf(rg, n0 + n1, aN));
            h = fmaf(zg, h - ng, ng);   // (1-z)*n + z*h

            if (cap) osw[s] = h;        // unit-0 lanes stage out (off-chain)
        }
        const float ov = osw[p];        // same-wave DS order covers this
        ob[c * CHUNK + p] = ov;         // 64B runs per 16-lane group
    }
}

// ---------------- fallback: R8-style LDS h exchange ----------------
__device__ void gru_lds(
    const float* __restrict__ xp, float* __restrict__ ob,
    const float* __restrict__ w_ih, const float* __restrict__ w_hh,
    const float* __restrict__ bias, const float* __restrict__ bias_n,
    float* __restrict__ x_lds, float* __restrict__ out_stage,
    float* __restrict__ h2, int lane, int hf, int p)
{
    float wr[32], wz[32], wn[32];
#pragma unroll
    for (int k = 0; k < 32; ++k) {
        wr[k] = w_hh[(size_t)p * GRU_H + k];
        wz[k] = w_hh[(size_t)(GRU_H + p) * GRU_H + k];
        wn[k] = w_hh[(size_t)(2 * GRU_H + p) * GRU_H + k];
    }
    float wir[GRU_D], wiz[GRU_D], win[GRU_D];
#pragma unroll
    for (int d = 0; d < GRU_D; ++d) {
        wir[d] = w_ih[(size_t)p * GRU_D + d];
        wiz[d] = w_ih[(size_t)(GRU_H + p) * GRU_D + d];
        win[d] = w_ih[(size_t)(2 * GRU_H + p) * GRU_D + d];
    }
    const float bR = bias[p];
    const float bZ = bias[GRU_H + p];
    const float bN = bias[2 * GRU_H + p] + bias_n[p];

    float* hw = h2 + 48 * hf + p;
    const float4* hv = (const float4*)(h2 + 48 * hf);
    float* xw = x_lds + 96 * hf;
    const float* xr = x_lds + 96 * hf;
    float* osw = out_stage + 32 * hf;
    const bool cap = (lane & 47) == 0;

    float h = 0.0f;
    *hw = 0.0f;
    float xa = xp[p], xb = xp[32 + p], xc = xp[64 + p];

    for (int c = 0; c < GRU_T / CHUNK; ++c) {
        xw[p] = xa; xw[32 + p] = xb; xw[64 + p] = xc;
        if (c + 1 < GRU_T / CHUNK) {
            const size_t nb = (size_t)(c + 1) * (CHUNK * GRU_D);
            xa = xp[nb + p]; xb = xp[nb + 32 + p]; xc = xp[nb + 64 + p];
        }
#pragma unroll 8
        for (int s = 0; s < CHUNK; ++s) {
            const float x0 = xr[3 * s + 0];
            const float x1 = xr[3 * s + 1];
            const float x2 = xr[3 * s + 2];
            float4 hk[8];
#pragma unroll
            for (int q = 0; q < 8; ++q) hk[q] = hv[q];

            const float aR = fmaf(wir[2], x2, fmaf(wir[1], x1, fmaf(wir[0], x0, bR)));
            const float aZ = fmaf(wiz[2], x2, fmaf(wiz[1], x1, fmaf(wiz[0], x0, bZ)));
            const float aN = fmaf(win[2], x2, fmaf(win[1], x1, fmaf(win[0], x0, bN)));

            float r0 = aR, r1 = 0.f, z0 = aZ, z1 = 0.f, n0 = 0.f, n1 = 0.f;
#pragma unroll
            for (int q = 0; q < 8; ++q) {
                const float4 v = hk[q];
                r0 = fmaf(wr[4*q+0], v.x, r0); r1 = fmaf(wr[4*q+1], v.y, r1);
                r0 = fmaf(wr[4*q+2], v.z, r0); r1 = fmaf(wr[4*q+3], v.w, r1);
                z0 = fmaf(wz[4*q+0], v.x, z0); z1 = fmaf(wz[4*q+1], v.y, z1);
                z0 = fmaf(wz[4*q+2], v.z, z0); z1 = fmaf(wz[4*q+3], v.w, z1);
                n0 = fmaf(wn[4*q+0], v.x, n0); n1 = fmaf(wn[4*q+1], v.y, n1);
                n0 = fmaf(wn[4*q+2], v.z, n0); n1 = fmaf(wn[4*q+3], v.w, n1);
            }
            const float rg = fast_sigmoid(r0 + r1);
            const float zg = fast_sigmoid(z0 + z1);
            const float ng = fast_tanh(fmaf(rg, n0 + n1, aN));
            h = fmaf(zg, h - ng, ng);
            if (cap) osw[s] = h;
            *hw = h;
        }
        const float ov = osw[p];
        ob[c * CHUNK + p] = ov;
    }
}

__global__ __launch_bounds__(64, 1) void gru_scan_kernel(
    const float* __restrict__ inp, const float* __restrict__ w_ih,
    const float* __restrict__ w_hh, const float* __restrict__ bias,
    const float* __restrict__ bias_n, float* __restrict__ out)
{
    __shared__ __align__(16) float x_lds[2 * CHUNK * GRU_D];  // per-seq x chunk
    __shared__ __align__(16) float out_stage[2 * CHUNK];      // per-seq out
    __shared__ __align__(16) float h2[80];                    // fallback only

    const int lane = threadIdx.x;            // 0..63
    const int hf   = (lane >> 4) & 1;        // seq select (bit4)
    const int p    = (lane & 15) + 16 * (lane >> 5);  // owned unit / IO idx
    const size_t seq = 2 * (size_t)blockIdx.x + hf;

    const float* xp = inp + seq * (size_t)(GRU_T * GRU_D);
    float*       ob = out + seq * (size_t)GRU_T;

    // ---- one-time probes (ballot-verified, wave-uniform result) ----
    int dir = 0;        // DPP rotation direction; 0 = failed
    bool swapok = false, sel = false;
    {
        const int li = lane & 15;
        const int d1 = __builtin_amdgcn_update_dpp(0, li, 0x121, 0xF, 0xF, false);
        if (__ballot(d1 == ((li + 1) & 15)) == ~0ULL)       dir = 1;
        else if (__ballot(d1 == ((li + 15) & 15)) == ~0ULL) dir = -1;

        const unsigned ul = (unsigned)lane;
        uint2v q = __builtin_amdgcn_permlane32_swap(ul, ul, false, false);
        const unsigned want = ul ^ 32u;
        const bool okA = __ballot(q.x == want) == ~0ULL;
        const bool okB = __ballot(q.y == want) == ~0ULL;
        swapok = okA || okB;
        sel = okA;
    }

    if (dir != 0 && swapok) {
        if (sel) gru_fast<true >(xp, ob, w_ih, w_hh, bias, bias_n,
                                 x_lds, out_stage, lane, hf, p, dir);
        else     gru_fast<false>(xp, ob, w_ih, w_hh, bias, bias_n,
                                 x_lds, out_stage, lane, hf, p, dir);
    } else {
        gru_lds(xp, ob, w_ih, w_hh, bias, bias_n,
                x_lds, out_stage, h2, lane, hf, p);
    }
}

extern "C" void kernel_launch(void* const* d_in, const int* in_sizes, int n_in,
                              void* d_out, int out_size, void* d_ws, size_t ws_size,
                              hipStream_t stream) {
    const float* inp    = (const float*)d_in[0];
    const float* w_ih   = (const float*)d_in[1];
    const float* w_hh   = (const float*)d_in[2];
    const float* bias   = (const float*)d_in[3];
    const float* bias_n = (const float*)d_in[4];
    float* out = (float*)d_out;

    dim3 grid(GRU_B / 2);
    dim3 block(64);
    gru_scan_kernel<<<grid, block, 0, stream>>>(inp, w_ih, w_hh, bias, bias_n, out);
}

// Round 8
// 601.188 us; speedup vs baseline: 1.1597x; 1.0193x over previous
//
#include <hip/hip_runtime.h>

// GRU scan: B=2048, T=2048, D=3, H=32. out[b,t] = h_new[b,t][0].
// Round-10: R9 register-h structure + per-step latency removal.
// R9 counters: fast path ran (VGPR 108), wall 717 cy/step, ~300-400 cy
// stall at 1 wave/SIMD. Sources: per-step x ds_read latency exposed by
// lgkm wait before projections; DPP->swap serial pairs; 16-deep FMA
// chains; capture ds_write polluting the DS queue; x bank aliasing
// (1.4e7 conflicts). Fixes:
//  - x one-step-ahead REGISTER prefetch (reads for s+1 issued at s,
//    consumed next step: ~300cy gap >> DS latency);
//  - capture via readfirstlane/readlane (VALU, off-chain; DS queue is
//    now pure x-reads -> clean counted lgkm waits);
//  - other-block rotations: 1 permlane32_swap of h + 15 DPP on the
//    swapped value (parallel rotation sets, was 16 serial swaps);
//  - 4-way accumulator splits per gate (chain 16 -> 8 deep);
//  - seq-B x base padded 96 -> 104 floats (bank offset 8, no aliasing).

#define GRU_B 2048
#define GRU_T 2048
#define GRU_D 3
#define GRU_H 32
#define CHUNK 32
#define XPAD 104  // seq-B x base offset (bank +8)

typedef unsigned int uint2v __attribute__((ext_vector_type(2)));

__device__ __forceinline__ float fast_sigmoid(float x) {
    float e = __expf(-x);                    // v_mul(log2e)+v_exp
    return __builtin_amdgcn_rcpf(1.0f + e);  // e=inf -> 0 (correct limit)
}
__device__ __forceinline__ float fast_tanh(float x) {
    float e = __expf(2.0f * x);              // overflow -> inf -> tanh=1
    return 1.0f - 2.0f * __builtin_amdgcn_rcpf(e + 1.0f);
}

// DPP row_ror:N = 0x120+N; all rows/banks, no bound ctrl.
#define DPPF(v, CTRL) __int_as_float(__builtin_amdgcn_update_dpp( \
    0, __float_as_int(v), (CTRL), 0xF, 0xF, false))

template<bool SEL>
__device__ __forceinline__ float swap32(float v) {
    uint2v r = __builtin_amdgcn_permlane32_swap(
        __float_as_uint(v), __float_as_uint(v), false, false);
    return __uint_as_float(SEL ? r.x : r.y);
}

// ---------------- fast path: register h, DPP + permlane32 ----------------
template<bool SEL>
__device__ void gru_fast(
    const float* __restrict__ xp, float* __restrict__ ob,
    const float* __restrict__ w_ih, const float* __restrict__ w_hh,
    const float* __restrict__ bias, const float* __restrict__ bias_n,
    float* __restrict__ x_lds, int lane, int hf, int p, int dir)
{
    const int li = lane & 15;          // index within 16-row
    const int bb = 16 * (lane >> 5);   // own unit-block base (0 or 16)

    // weights permuted to rotation order: FMA j pairs rotation j.
    float wrO[16], wrX[16], wzO[16], wzX[16], wnO[16], wnX[16];
#pragma unroll
    for (int j = 0; j < 16; ++j) {
        const int kk = (li + dir * j + 16) & 15;
        const int kown = bb + kk;
        const int koth = (bb ^ 16) + kk;
        wrO[j] = w_hh[(size_t)p * GRU_H + kown];
        wrX[j] = w_hh[(size_t)p * GRU_H + koth];
        wzO[j] = w_hh[(size_t)(GRU_H + p) * GRU_H + kown];
        wzX[j] = w_hh[(size_t)(GRU_H + p) * GRU_H + koth];
        wnO[j] = w_hh[(size_t)(2 * GRU_H + p) * GRU_H + kown];
        wnX[j] = w_hh[(size_t)(2 * GRU_H + p) * GRU_H + koth];
    }
    float wir[GRU_D], wiz[GRU_D], win[GRU_D];
#pragma unroll
    for (int d = 0; d < GRU_D; ++d) {
        wir[d] = w_ih[(size_t)p * GRU_D + d];
        wiz[d] = w_ih[(size_t)(GRU_H + p) * GRU_D + d];
        win[d] = w_ih[(size_t)(2 * GRU_H + p) * GRU_D + d];
    }
    const float bR = bias[p];
    const float bZ = bias[GRU_H + p];
    const float bN = bias[2 * GRU_H + p] + bias_n[p];

    float* xw = x_lds + XPAD * hf;
    const float* xr = x_lds + XPAD * hf;

    float h = 0.0f;
    // global prefetch of chunk 0 (chunk-ahead; HBM-safe)
    float xa = xp[p], xb = xp[32 + p], xc = xp[64 + p];

    for (int c = 0; c < GRU_T / CHUNK; ++c) {
        // stage current chunk (regs -> LDS); prefetch next chunk (global)
        xw[p] = xa; xw[32 + p] = xb; xw[64 + p] = xc;
        if (c + 1 < GRU_T / CHUNK) {
            const size_t nb = (size_t)(c + 1) * (CHUNK * GRU_D);
            xa = xp[nb + p]; xb = xp[nb + 32 + p]; xc = xp[nb + 64 + p];
        }
        // step-0 x: read now (in-order behind the stage writes; exposed
        // wait once per chunk only)
        float x0c = xr[0], x1c = xr[1], x2c = xr[2];
        float outreg = 0.0f;

#pragma unroll 8
        for (int s = 0; s < CHUNK; ++s) {
            // projections consume the prefetched x (their lgkm wait covers
            // reads issued a full step ago -> no stall)
            const float aR = fmaf(wir[2], x2c, fmaf(wir[1], x1c, fmaf(wir[0], x0c, bR)));
            const float aZ = fmaf(wiz[2], x2c, fmaf(wiz[1], x1c, fmaf(wiz[0], x0c, bZ)));
            const float aN = fmaf(win[2], x2c, fmaf(win[1], x1c, fmaf(win[0], x0c, bN)));

            // issue next step's x reads (consumed next iteration)
            float x0n = x0c, x1n = x1c, x2n = x2c;
            if (s + 1 < CHUNK) {
                x0n = xr[3 * (s + 1) + 0];
                x1n = xr[3 * (s + 1) + 1];
                x2n = xr[3 * (s + 1) + 2];
            }

            // rotations: own block from h, other block from swapped h
            const float hsw = swap32<SEL>(h);
            float hr_[16], ho_[16];
            hr_[0] = h;    ho_[0] = hsw;
            hr_[1]  = DPPF(h, 0x121);   ho_[1]  = DPPF(hsw, 0x121);
            hr_[2]  = DPPF(h, 0x122);   ho_[2]  = DPPF(hsw, 0x122);
            hr_[3]  = DPPF(h, 0x123);   ho_[3]  = DPPF(hsw, 0x123);
            hr_[4]  = DPPF(h, 0x124);   ho_[4]  = DPPF(hsw, 0x124);
            hr_[5]  = DPPF(h, 0x125);   ho_[5]  = DPPF(hsw, 0x125);
            hr_[6]  = DPPF(h, 0x126);   ho_[6]  = DPPF(hsw, 0x126);
            hr_[7]  = DPPF(h, 0x127);   ho_[7]  = DPPF(hsw, 0x127);
            hr_[8]  = DPPF(h, 0x128);   ho_[8]  = DPPF(hsw, 0x128);
            hr_[9]  = DPPF(h, 0x129);   ho_[9]  = DPPF(hsw, 0x129);
            hr_[10] = DPPF(h, 0x12A);   ho_[10] = DPPF(hsw, 0x12A);
            hr_[11] = DPPF(h, 0x12B);   ho_[11] = DPPF(hsw, 0x12B);
            hr_[12] = DPPF(h, 0x12C);   ho_[12] = DPPF(hsw, 0x12C);
            hr_[13] = DPPF(h, 0x12D);   ho_[13] = DPPF(hsw, 0x12D);
            hr_[14] = DPPF(h, 0x12E);   ho_[14] = DPPF(hsw, 0x12E);
            hr_[15] = DPPF(h, 0x12F);   ho_[15] = DPPF(hsw, 0x12F);

            // 96 FMAs, 4 accumulator chains per gate (8 deep each)
            float rO0 = aR, rO1 = 0.f, rX0 = 0.f, rX1 = 0.f;
            float zO0 = aZ, zO1 = 0.f, zX0 = 0.f, zX1 = 0.f;
            float nO0 = 0.f, nO1 = 0.f, nX0 = 0.f, nX1 = 0.f;
#pragma unroll
            for (int j = 0; j < 8; ++j) {
                rO0 = fmaf(wrO[j],     hr_[j],     rO0);
                rO1 = fmaf(wrO[j + 8], hr_[j + 8], rO1);
                rX0 = fmaf(wrX[j],     ho_[j],     rX0);
                rX1 = fmaf(wrX[j + 8], ho_[j + 8], rX1);
                zO0 = fmaf(wzO[j],     hr_[j],     zO0);
                zO1 = fmaf(wzO[j + 8], hr_[j + 8], zO1);
                zX0 = fmaf(wzX[j],     ho_[j],     zX0);
                zX1 = fmaf(wzX[j + 8], ho_[j + 8], zX1);
                nO0 = fmaf(wnO[j],     hr_[j],     nO0);
                nO1 = fmaf(wnO[j + 8], hr_[j + 8], nO1);
                nX0 = fmaf(wnX[j],     ho_[j],     nX0);
                nX1 = fmaf(wnX[j + 8], ho_[j + 8], nX1);
            }
            const float rs = (rO0 + rO1) + (rX0 + rX1);
            const float zs = (zO0 + zO1) + (zX0 + zX1);
            const float ns = (nO0 + nO1) + (nX0 + nX1);

            const float rg = fast_sigmoid(rs);
            const float zg = fast_sigmoid(zs);
            const float ng = fast_tanh(fmaf(rg, ns, aN));
            h = fmaf(zg, h - ng, ng);   // (1-z)*n + z*h

            // capture out[t]=h_new[t][0] via VALU broadcast (off-chain):
            // lane 0 = seq A unit 0, lane 16 = seq B unit 0.
            const float h0A = __uint_as_float(
                (unsigned)__builtin_amdgcn_readfirstlane(__float_as_int(h)));
            const float h0B = __uint_as_float(
                (unsigned)__builtin_amdgcn_readlane(__float_as_int(h), 16));
            const float want = hf ? h0B : h0A;
            if (p == s) outreg = want;

            x0c = x0n; x1c = x1n; x2c = x2n;
        }
        ob[c * CHUNK + p] = outreg;  // 64B runs per 16-lane group
    }
}

// ---------------- fallback: R8-style LDS h exchange ----------------
__device__ void gru_lds(
    const float* __restrict__ xp, float* __restrict__ ob,
    const float* __restrict__ w_ih, const float* __restrict__ w_hh,
    const float* __restrict__ bias, const float* __restrict__ bias_n,
    float* __restrict__ x_lds, float* __restrict__ out_stage,
    float* __restrict__ h2, int lane, int hf, int p)
{
    float wr[32], wz[32], wn[32];
#pragma unroll
    for (int k = 0; k < 32; ++k) {
        wr[k] = w_hh[(size_t)p * GRU_H + k];
        wz[k] = w_hh[(size_t)(GRU_H + p) * GRU_H + k];
        wn[k] = w_hh[(size_t)(2 * GRU_H + p) * GRU_H + k];
    }
    float wir[GRU_D], wiz[GRU_D], win[GRU_D];
#pragma unroll
    for (int d = 0; d < GRU_D; ++d) {
        wir[d] = w_ih[(size_t)p * GRU_D + d];
        wiz[d] = w_ih[(size_t)(GRU_H + p) * GRU_D + d];
        win[d] = w_ih[(size_t)(2 * GRU_H + p) * GRU_D + d];
    }
    const float bR = bias[p];
    const float bZ = bias[GRU_H + p];
    const float bN = bias[2 * GRU_H + p] + bias_n[p];

    float* hw = h2 + 48 * hf + p;
    const float4* hv = (const float4*)(h2 + 48 * hf);
    float* xw = x_lds + XPAD * hf;
    const float* xr = x_lds + XPAD * hf;
    float* osw = out_stage + 32 * hf;
    const bool cap = (lane & 47) == 0;

    float h = 0.0f;
    *hw = 0.0f;
    float xa = xp[p], xb = xp[32 + p], xc = xp[64 + p];

    for (int c = 0; c < GRU_T / CHUNK; ++c) {
        xw[p] = xa; xw[32 + p] = xb; xw[64 + p] = xc;
        if (c + 1 < GRU_T / CHUNK) {
            const size_t nb = (size_t)(c + 1) * (CHUNK * GRU_D);
            xa = xp[nb + p]; xb = xp[nb + 32 + p]; xc = xp[nb + 64 + p];
        }
#pragma unroll 8
        for (int s = 0; s < CHUNK; ++s) {
            const float x0 = xr[3 * s + 0];
            const float x1 = xr[3 * s + 1];
            const float x2 = xr[3 * s + 2];
            float4 hk[8];
#pragma unroll
            for (int q = 0; q < 8; ++q) hk[q] = hv[q];

            const float aR = fmaf(wir[2], x2, fmaf(wir[1], x1, fmaf(wir[0], x0, bR)));
            const float aZ = fmaf(wiz[2], x2, fmaf(wiz[1], x1, fmaf(wiz[0], x0, bZ)));
            const float aN = fmaf(win[2], x2, fmaf(win[1], x1, fmaf(win[0], x0, bN)));

            float r0 = aR, r1 = 0.f, z0 = aZ, z1 = 0.f, n0 = 0.f, n1 = 0.f;
#pragma unroll
            for (int q = 0; q < 8; ++q) {
                const float4 v = hk[q];
                r0 = fmaf(wr[4*q+0], v.x, r0); r1 = fmaf(wr[4*q+1], v.y, r1);
                r0 = fmaf(wr[4*q+2], v.z, r0); r1 = fmaf(wr[4*q+3], v.w, r1);
                z0 = fmaf(wz[4*q+0], v.x, z0); z1 = fmaf(wz[4*q+1], v.y, z1);
                z0 = fmaf(wz[4*q+2], v.z, z0); z1 = fmaf(wz[4*q+3], v.w, z1);
                n0 = fmaf(wn[4*q+0], v.x, n0); n1 = fmaf(wn[4*q+1], v.y, n1);
                n0 = fmaf(wn[4*q+2], v.z, n0); n1 = fmaf(wn[4*q+3], v.w, n1);
            }
            const float rg = fast_sigmoid(r0 + r1);
            const float zg = fast_sigmoid(z0 + z1);
            const float ng = fast_tanh(fmaf(rg, n0 + n1, aN));
            h = fmaf(zg, h - ng, ng);
            if (cap) osw[s] = h;
            *hw = h;
        }
        const float ov = osw[p];
        ob[c * CHUNK + p] = ov;
    }
}

__global__ __launch_bounds__(64, 1) void gru_scan_kernel(
    const float* __restrict__ inp, const float* __restrict__ w_ih,
    const float* __restrict__ w_hh, const float* __restrict__ bias,
    const float* __restrict__ bias_n, float* __restrict__ out)
{
    __shared__ __align__(16) float x_lds[2 * XPAD];       // per-seq x chunk
    __shared__ __align__(16) float out_stage[2 * CHUNK];  // fallback only
    __shared__ __align__(16) float h2[80];                // fallback only

    const int lane = threadIdx.x;            // 0..63
    const int hf   = (lane >> 4) & 1;        // seq select (bit4)
    const int p    = (lane & 15) + 16 * (lane >> 5);  // owned unit / IO idx
    const size_t seq = 2 * (size_t)blockIdx.x + hf;

    const float* xp = inp + seq * (size_t)(GRU_T * GRU_D);
    float*       ob = out + seq * (size_t)GRU_T;

    // ---- one-time probes (ballot-verified, wave-uniform result) ----
    int dir = 0;        // DPP rotation direction; 0 = failed
    bool swapok = false, sel = false;
    {
        const int li = lane & 15;
        const int d1 = __builtin_amdgcn_update_dpp(0, li, 0x121, 0xF, 0xF, false);
        if (__ballot(d1 == ((li + 1) & 15)) == ~0ULL)       dir = 1;
        else if (__ballot(d1 == ((li + 15) & 15)) == ~0ULL) dir = -1;

        const unsigned ul = (unsigned)lane;
        uint2v q = __builtin_amdgcn_permlane32_swap(ul, ul, false, false);
        const unsigned want = ul ^ 32u;
        const bool okA = __ballot(q.x == want) == ~0ULL;
        const bool okB = __ballot(q.y == want) == ~0ULL;
        swapok = okA || okB;
        sel = okA;
    }

    if (dir != 0 && swapok) {
        if (sel) gru_fast<true >(xp, ob, w_ih, w_hh, bias, bias_n,
                                 x_lds, lane, hf, p, dir);
        else     gru_fast<false>(xp, ob, w_ih, w_hh, bias, bias_n,
                                 x_lds, lane, hf, p, dir);
    } else {
        gru_lds(xp, ob, w_ih, w_hh, bias, bias_n,
                x_lds, out_stage, h2, lane, hf, p);
    }
}

extern "C" void kernel_launch(void* const* d_in, const int* in_sizes, int n_in,
                              void* d_out, int out_size, void* d_ws, size_t ws_size,
                              hipStream_t stream) {
    const float* inp    = (const float*)d_in[0];
    const float* w_ih   = (const float*)d_in[1];
    const float* w_hh   = (const float*)d_in[2];
    const float* bias   = (const float*)d_in[3];
    const float* bias_n = (const float*)d_in[4];
    float* out = (float*)d_out;

    dim3 grid(GRU_B / 2);
    dim3 block(64);
    gru_scan_kernel<<<grid, block, 0, stream>>>(inp, w_ih, w_hh, bias, bias_n, out);
}